// Round 1
// baseline (52.417 us; speedup 1.0000x reference)
//
#include <hip/hip_runtime.h>
#include <math.h>

// Kaldi LinearResample 16000 -> 22050, LPW=6
// gcd=50, P = 22050/50 = 441 output phases, STRIDE = 16000/50 = 320 input samples
// window width W = 13 taps (verified analytically: ceil/floor of +/- 6.0606 span)
#define ORIG_F 16000
#define NEW_F  22050
#define LPW    6
#define P      441
#define STRIDE 320
#define W      13

#ifndef M_PI
#define M_PI 3.14159265358979323846
#endif

// Rebuild the Kaldi filter bank in float64 (matches numpy reference math),
// ~5.7K weights -> negligible cost, deterministic each launch.
__global__ void build_table_kernel(float* __restrict__ wtab, int* __restrict__ fitab) {
    int p = blockIdx.x * blockDim.x + threadIdx.x;
    if (p >= P) return;
    const double cutoff = 0.99 * 0.5 * (double)ORIG_F;   // min(ORIG,NEW) = 16000
    const double ww = (double)LPW / (2.0 * cutoff);
    double out_t = (double)p / (double)NEW_F;
    double min_i = ceil((out_t - ww) * (double)ORIG_F);
    fitab[p] = (int)min_i;
    for (int j = 0; j < W; ++j) {
        double inp_i = min_i + (double)j;
        double dt = inp_i / (double)ORIG_F - out_t;
        double wv = 0.0;
        if (fabs(dt) < ww) {
            wv = 0.5 * (1.0 + cos(2.0 * M_PI * cutoff / (double)LPW * dt));
            if (dt != 0.0)
                wv *= sin(2.0 * M_PI * cutoff * dt) / (M_PI * dt);
            else
                wv *= 2.0 * cutoff;
        }
        wv /= (double)ORIG_F;
        wtab[p * W + j] = (float)wv;
    }
}

__global__ __launch_bounds__(256) void resample_kernel(
    const float* __restrict__ x, const float* __restrict__ wtab,
    const int* __restrict__ fitab, float* __restrict__ out,
    int n, int tot)
{
    __shared__ float sw[P * W];   // 22932 B
    __shared__ int   sfi[P];      //  1764 B
    for (int i = threadIdx.x; i < P * W; i += blockDim.x) sw[i] = wtab[i];
    for (int i = threadIdx.x; i < P;     i += blockDim.x) sfi[i] = fitab[i];
    __syncthreads();

    const int b = blockIdx.y;
    const float* __restrict__ xb = x + (size_t)b * n;
    float* __restrict__ ob = out + (size_t)b * tot;

    const int tstride = gridDim.x * blockDim.x;
    for (int t = blockIdx.x * blockDim.x + threadIdx.x; t < tot; t += tstride) {
        int phase = t % P;
        int ti    = t / P;
        int base  = sfi[phase] + ti * STRIDE;
        const float* wr = &sw[phase * W];
        float acc = 0.f;
        if (base >= 0 && base + W <= n) {
            #pragma unroll
            for (int j = 0; j < W; ++j)
                acc += xb[base + j] * wr[j];
        } else {
            #pragma unroll
            for (int j = 0; j < W; ++j) {
                int ii = base + j;
                float xv = (ii >= 0 && ii < n) ? xb[ii] : 0.f;
                acc += xv * wr[j];
            }
        }
        ob[t] = acc;
    }
}

extern "C" void kernel_launch(void* const* d_in, const int* in_sizes, int n_in,
                              void* d_out, int out_size, void* d_ws, size_t ws_size,
                              hipStream_t stream) {
    const float* x = (const float*)d_in[0];
    float* out = (float*)d_out;

    const int B = 8;                       // setup_inputs: (8, 960000) float32
    const int n = in_sizes[0] / B;         // 960000

    // Kaldi GetNumOutputSamples: tick=lcm, tpi=441, tpo=320
    long long interval = (long long)n * P;
    long long last = interval / STRIDE;
    if (last * STRIDE == interval) last -= 1;
    const int tot = (int)(last + 1);       // 1,323,000

    float* wtab = (float*)d_ws;
    int*   fitab = (int*)((char*)d_ws + (size_t)P * W * sizeof(float));

    build_table_kernel<<<(P + 63) / 64, 64, 0, stream>>>(wtab, fitab);

    // Capped grid + grid-stride: 256 x 8 = 2048 blocks so the 23KB LDS weight
    // staging happens only 2048x (~50 MB L2 traffic) instead of 41K x (~1 GB).
    dim3 grid(256, B);
    resample_kernel<<<grid, 256, 0, stream>>>(x, wtab, fitab, out, n, tot);
}

// Round 2
// 38.549 us; speedup vs baseline: 1.3597x; 1.3597x over previous
//
#include <hip/hip_runtime.h>
#include <math.h>

// Kaldi LinearResample 16000 -> 22050, LPW=6
// gcd=50, P=441 phases, STRIDE=320 input samples per cycle, W=13 taps.
// Key facts: tot = 1,323,000 = 441*3000 exactly; STRIDE%4==0 so the
// alignment of base = fi[p]+320m depends only on the phase p. We pad each
// phase's 13 taps into a 16-tap row aligned to abase[p]=fi[p]&~3, making
// every output = 4 aligned float4 loads + 16 FMAs (no LDS, no div/mod).
#define ORIG_F 16000
#define NEW_F  22050
#define LPW    6
#define P      441
#define STRIDE 320
#define W      13
#define W16    16
#define MPT    24      // m-steps per thread

#ifndef M_PI
#define M_PI 3.14159265358979323846
#endif

// One thread per (phase, padded-tap): 441*16 = 7056 threads, each does one
// f64 sin+cos (vs R1's 441 threads x 13 serial sincos = ~55us tail).
__global__ void build_table16_kernel(float* __restrict__ w16, int* __restrict__ abase) {
    int idx = blockIdx.x * blockDim.x + threadIdx.x;
    if (idx >= P * W16) return;
    int p  = idx >> 4;
    int jj = idx & 15;
    const double cutoff = 0.99 * 0.5 * (double)ORIG_F;   // min(ORIG,NEW)=16000
    const double ww = (double)LPW / (2.0 * cutoff);
    double out_t = (double)p / (double)NEW_F;
    double min_i = ceil((out_t - ww) * (double)ORIG_F);
    int fi = (int)min_i;
    int ab = fi & ~3;
    int s  = fi & 3;
    if (jj == 0) abase[p] = ab;
    int j = jj - s;                       // actual tap index
    float wf = 0.f;
    if (j >= 0 && j < W) {
        double dt = (min_i + (double)j) / (double)ORIG_F - out_t;
        double wv = 0.0;
        if (fabs(dt) < ww) {
            wv = 0.5 * (1.0 + cos(2.0 * M_PI * cutoff / (double)LPW * dt));
            if (dt != 0.0) wv *= sin(2.0 * M_PI * cutoff * dt) / (M_PI * dt);
            else           wv *= 2.0 * cutoff;
        }
        wv /= (double)ORIG_F;
        wf = (float)wv;
    }
    w16[idx] = wf;
}

// Block = 448 threads (7 waves); thread p<441 owns phase p and MPT m-steps.
// Weights: 16 registers per thread, read once from global (28KB table, L2-hot).
// Stores: lanes = consecutive phases => contiguous 441-float rows, coalesced.
// Loads: neighbors' windows overlap (~0.73 floats/phase) => few lines/wave.
__global__ __launch_bounds__(448) void resample2_kernel(
    const float* __restrict__ x, const float* __restrict__ w16,
    const int* __restrict__ abase, float* __restrict__ out,
    int n, int tot)
{
    int p = threadIdx.x;
    if (p >= P) return;
    const int b  = blockIdx.y;
    const int m0 = blockIdx.x * MPT;
    const float* __restrict__ xb = x + (size_t)b * n;
    float* __restrict__ ob = out + (size_t)b * tot;

    float4 wv0 = ((const float4*)w16)[p * 4 + 0];
    float4 wv1 = ((const float4*)w16)[p * 4 + 1];
    float4 wv2 = ((const float4*)w16)[p * 4 + 2];
    float4 wv3 = ((const float4*)w16)[p * 4 + 3];
    const int ab = abase[p];

    #pragma unroll 4
    for (int k = 0; k < MPT; ++k) {
        const int m = m0 + k;
        const int t = m * P + p;
        if (t >= tot) break;
        const int base = ab + m * STRIDE;
        float4 x0, x1, x2, x3;
        if (base >= 0 && base + W16 <= n) {
            const float4* xp4 = (const float4*)(xb + base);
            x0 = xp4[0]; x1 = xp4[1]; x2 = xp4[2]; x3 = xp4[3];
        } else {
            // edge cycles only (m==0 left pad, last m right pad)
            float xs[16];
            #pragma unroll
            for (int jj = 0; jj < W16; ++jj) {
                int ii = base + jj;
                xs[jj] = (ii >= 0 && ii < n) ? xb[ii] : 0.f;
            }
            x0 = make_float4(xs[0], xs[1], xs[2], xs[3]);
            x1 = make_float4(xs[4], xs[5], xs[6], xs[7]);
            x2 = make_float4(xs[8], xs[9], xs[10], xs[11]);
            x3 = make_float4(xs[12], xs[13], xs[14], xs[15]);
        }
        float acc = x0.x * wv0.x + x0.y * wv0.y + x0.z * wv0.z + x0.w * wv0.w
                  + x1.x * wv1.x + x1.y * wv1.y + x1.z * wv1.z + x1.w * wv1.w
                  + x2.x * wv2.x + x2.y * wv2.y + x2.z * wv2.z + x2.w * wv2.w
                  + x3.x * wv3.x + x3.y * wv3.y + x3.z * wv3.z + x3.w * wv3.w;
        ob[t] = acc;
    }
}

extern "C" void kernel_launch(void* const* d_in, const int* in_sizes, int n_in,
                              void* d_out, int out_size, void* d_ws, size_t ws_size,
                              hipStream_t stream) {
    const float* x = (const float*)d_in[0];
    float* out = (float*)d_out;

    const int B = 8;                       // (8, 960000) float32
    const int n = in_sizes[0] / B;         // 960000

    // Kaldi GetNumOutputSamples
    long long interval = (long long)n * P;
    long long last = interval / STRIDE;
    if (last * STRIDE == interval) last -= 1;
    const int tot = (int)(last + 1);       // 1,323,000 = 441*3000

    float* w16  = (float*)d_ws;
    int*   abase = (int*)((char*)d_ws + (size_t)P * W16 * sizeof(float));

    build_table16_kernel<<<(P * W16 + 255) / 256, 256, 0, stream>>>(w16, abase);

    const int mcyc = (tot + P - 1) / P;           // 3000
    const int nblk = (mcyc + MPT - 1) / MPT;      // 125
    dim3 grid(nblk, B);
    resample2_kernel<<<grid, 448, 0, stream>>>(x, w16, abase, out, n, tot);
}

// Round 3
// 30.351 us; speedup vs baseline: 1.7270x; 1.2701x over previous
//
#include <hip/hip_runtime.h>
#include <math.h>

// Kaldi LinearResample 16000 -> 22050, LPW=6.
// P=441 phases, STRIDE=320, W=13 taps, tot = 441*3000.
// R2 insight: group GPW=3 consecutive phases per thread. fi[] spans <=2 within
// a group, so ONE aligned 20-float window (5x float4) feeds all 3 outputs:
// 1.67 float4 loads/output vs 4. Per-phase weights are re-expressed as a
// 20-tap row relative to the group's aligned base (zeros outside the 13 real
// taps), held in 15 float4 registers and reused across MPT m-steps.
#define ORIG_F 16000
#define NEW_F  22050
#define LPW    6
#define P      441
#define STRIDE 320
#define W      13
#define GPW    3
#define NG     147      // 441/3
#define W20    20
#define MPT    12       // m-steps per thread
#define MCH    250      // 3000/MPT
#define BATCH  8

#ifndef M_PI
#define M_PI 3.14159265358979323846
#endif

__device__ __forceinline__ double kaldi_fi(int p, double* out_t) {
    const double cutoff = 0.99 * 0.5 * (double)ORIG_F;
    const double ww = (double)LPW / (2.0 * cutoff);
    double ot = (double)p / (double)NEW_F;
    *out_t = ot;
    return ceil((ot - ww) * (double)ORIG_F);
}

// One thread per (phase, padded tap j in [0,20)). Builds w20[p][j] = weight
// applied to x[gab[g] + j] for phase p (0 outside the 13-tap support), plus
// gab[g] = fi[3g] & ~3 (fi monotonic => group min).
__global__ void build_table20_kernel(float* __restrict__ w20, int* __restrict__ gab) {
    int idx = blockIdx.x * blockDim.x + threadIdx.x;
    if (idx >= P * W20) return;
    int p = idx / W20;
    int j = idx - p * W20;
    const double cutoff = 0.99 * 0.5 * (double)ORIG_F;
    const double ww = (double)LPW / (2.0 * cutoff);
    double out_t, out_t0;
    double min_i = kaldi_fi(p, &out_t);
    int fi = (int)min_i;
    int p0 = (p / GPW) * GPW;
    int fi0 = (int)kaldi_fi(p0, &out_t0);
    int ab = fi0 & ~3;
    if (j == 0 && p == p0) gab[p / GPW] = ab;
    int jt = ab + j - fi;                 // tap index for this window slot
    float wf = 0.f;
    if (jt >= 0 && jt < W) {
        double dt = (min_i + (double)jt) / (double)ORIG_F - out_t;
        double wv = 0.0;
        if (fabs(dt) < ww) {
            wv = 0.5 * (1.0 + cos(2.0 * M_PI * cutoff / (double)LPW * dt));
            if (dt != 0.0) wv *= sin(2.0 * M_PI * cutoff * dt) / (M_PI * dt);
            else           wv *= 2.0 * cutoff;
        }
        wv /= (double)ORIG_F;
        wf = (float)wv;
    }
    w20[p * W20 + j] = wf;
}

__device__ __forceinline__ float dot20(const float4& x0, const float4& x1,
                                       const float4& x2, const float4& x3,
                                       const float4& x4, const float4* w) {
    return x0.x*w[0].x + x0.y*w[0].y + x0.z*w[0].z + x0.w*w[0].w
         + x1.x*w[1].x + x1.y*w[1].y + x1.z*w[1].z + x1.w*w[1].w
         + x2.x*w[2].x + x2.y*w[2].y + x2.z*w[2].z + x2.w*w[2].w
         + x3.x*w[3].x + x3.y*w[3].y + x3.z*w[3].z + x3.w*w[3].w
         + x4.x*w[4].x + x4.y*w[4].y + x4.z*w[4].z + x4.w*w[4].w;
}

// Thread owns (batch b, m-chunk mc, phase-group g): 3 outputs x MPT m-steps.
// Consecutive lanes = consecutive groups -> loads of neighbors overlap within
// ~10 B, stores are dense. 60 FMA per 5 loads + 3 stores.
__global__ __launch_bounds__(256) void resample3_kernel(
    const float* __restrict__ x, const float* __restrict__ w20,
    const int* __restrict__ gab, float* __restrict__ out,
    int n, int tot)
{
    int tid = blockIdx.x * blockDim.x + threadIdx.x;
    int g    = tid % NG;
    int rest = tid / NG;
    int mc   = rest % MCH;
    int b    = rest / MCH;
    if (b >= BATCH) return;

    const float* __restrict__ xb = x + (size_t)b * n;
    float* __restrict__ ob = out + (size_t)b * tot;

    const float4* wp = (const float4*)(w20 + g * (GPW * W20));
    float4 w[15];
    #pragma unroll
    for (int i = 0; i < 15; ++i) w[i] = wp[i];
    const int ab = gab[g];
    const int m0 = mc * MPT;
    const int p0 = g * GPW;

    #pragma unroll 2
    for (int k = 0; k < MPT; ++k) {
        const int m = m0 + k;
        const int base = ab + m * STRIDE;
        float4 x0, x1, x2, x3, x4;
        if (base >= 0 && base + W20 <= n) {
            const float4* xp = (const float4*)(xb + base);
            x0 = xp[0]; x1 = xp[1]; x2 = xp[2]; x3 = xp[3]; x4 = xp[4];
        } else {
            float xs[W20];
            #pragma unroll
            for (int j = 0; j < W20; ++j) {
                int ii = base + j;
                xs[j] = (ii >= 0 && ii < n) ? xb[ii] : 0.f;
            }
            x0 = make_float4(xs[0], xs[1], xs[2], xs[3]);
            x1 = make_float4(xs[4], xs[5], xs[6], xs[7]);
            x2 = make_float4(xs[8], xs[9], xs[10], xs[11]);
            x3 = make_float4(xs[12], xs[13], xs[14], xs[15]);
            x4 = make_float4(xs[16], xs[17], xs[18], xs[19]);
        }
        float a0 = dot20(x0, x1, x2, x3, x4, &w[0]);
        float a1 = dot20(x0, x1, x2, x3, x4, &w[5]);
        float a2 = dot20(x0, x1, x2, x3, x4, &w[10]);
        const int t = m * P + p0;
        __builtin_nontemporal_store(a0, &ob[t]);
        __builtin_nontemporal_store(a1, &ob[t + 1]);
        __builtin_nontemporal_store(a2, &ob[t + 2]);
    }
}

extern "C" void kernel_launch(void* const* d_in, const int* in_sizes, int n_in,
                              void* d_out, int out_size, void* d_ws, size_t ws_size,
                              hipStream_t stream) {
    const float* x = (const float*)d_in[0];
    float* out = (float*)d_out;

    const int n = in_sizes[0] / BATCH;     // 960000

    // Kaldi GetNumOutputSamples
    long long interval = (long long)n * P;
    long long last = interval / STRIDE;
    if (last * STRIDE == interval) last -= 1;
    const int tot = (int)(last + 1);       // 1,323,000 = 441*3000

    float* w20 = (float*)d_ws;
    int*   gab = (int*)((char*)d_ws + (size_t)P * W20 * sizeof(float));

    build_table20_kernel<<<(P * W20 + 255) / 256, 256, 0, stream>>>(w20, gab);

    const long long nthreads = (long long)BATCH * MCH * NG;   // 294,000
    const int nblk = (int)((nthreads + 255) / 256);
    resample3_kernel<<<nblk, 256, 0, stream>>>(x, w20, gab, out, n, tot);
}